// Round 2
// baseline (24922.746 us; speedup 1.0000x reference)
//
#include <hip/hip_runtime.h>
#include <hip/hip_bf16.h>
#include <math.h>

#define B_ 32
#define N_ 256
#define DIM_ 384
#define H_ 6
#define DH_ 64
#define INNER_ 384
#define MLP_ 1536
#define DEPTH_ 12
#define T_ (B_ * N_)   // 8192 tokens

// block-wide reduce (sum if op==0, max if op==1); all threads get result.
// scratch must hold blockDim.x/64 floats.
__device__ __forceinline__ float block_reduce(float v, float* scratch, int op) {
    int lane = threadIdx.x & 63;
    int wid  = threadIdx.x >> 6;
    int nw   = blockDim.x >> 6;
    #pragma unroll
    for (int o = 32; o > 0; o >>= 1) {
        float other = __shfl_down(v, o);
        v = op ? fmaxf(v, other) : (v + other);
    }
    __syncthreads();             // protect scratch from previous use
    if (lane == 0) scratch[wid] = v;
    __syncthreads();
    float r = scratch[0];
    for (int w = 1; w < nw; ++w) r = op ? fmaxf(r, scratch[w]) : (r + scratch[w]);
    return r;
}

// ---------------- layernorm: one block (128 thr) per token ----------------
__global__ __launch_bounds__(128) void ln_kernel(
    const float* __restrict__ x, const float* __restrict__ g,
    const float* __restrict__ b, float* __restrict__ y)
{
    __shared__ float red[2];
    size_t row = blockIdx.x;
    int tid = threadIdx.x;
    const float* xr = x + row * DIM_;
    float v0 = xr[tid], v1 = xr[tid + 128], v2 = xr[tid + 256];
    float sum = block_reduce(v0 + v1 + v2, red, 0);
    float mu = sum * (1.0f / DIM_);
    float d0 = v0 - mu, d1 = v1 - mu, d2 = v2 - mu;
    float var = block_reduce(d0 * d0 + d1 * d1 + d2 * d2, red, 0) * (1.0f / DIM_);
    float rs = rsqrtf(var + 1e-5f);
    float* yr = y + row * DIM_;
    yr[tid]       = d0 * rs * g[tid]       + b[tid];
    yr[tid + 128] = d1 * rs * g[tid + 128] + b[tid + 128];
    yr[tid + 256] = d2 * rs * g[tid + 256] + b[tid + 256];
}

// ---------------- generic tiled GEMM: C[M,Nn] = A[M,K] @ W[K,Nn] (+bias)(+ls*·+resid) --------
// tile 64x64, K-step 16, 256 threads, each thread 4x4.
__global__ __launch_bounds__(256) void gemm_kernel(
    const float* __restrict__ A, const float* __restrict__ W,
    const float* __restrict__ bias, const float* __restrict__ ls,
    const float* __restrict__ resid, float* __restrict__ C,
    int M, int K, int Nn)
{
    __shared__ float sA[16][65];
    __shared__ float sW[16][64];
    int bm = blockIdx.x * 64, bn = blockIdx.y * 64;
    int tid = threadIdx.x;
    int tx = tid & 15, ty = tid >> 4;
    float acc[4][4] = {};
    for (int k0 = 0; k0 < K; k0 += 16) {
        {
            int kk = tid & 15, mm0 = tid >> 4;
            #pragma unroll
            for (int r = 0; r < 4; ++r) {
                int mm = mm0 + r * 16;
                sA[kk][mm] = A[(size_t)(bm + mm) * K + k0 + kk];
            }
        }
        {
            int nn = tid & 63, kk0 = tid >> 6;
            #pragma unroll
            for (int r = 0; r < 4; ++r) {
                int kk = kk0 + r * 4;
                sW[kk][nn] = W[(size_t)(k0 + kk) * Nn + bn + nn];
            }
        }
        __syncthreads();
        #pragma unroll
        for (int kk = 0; kk < 16; ++kk) {
            float a[4], b[4];
            #pragma unroll
            for (int i = 0; i < 4; ++i) a[i] = sA[kk][ty * 4 + i];
            #pragma unroll
            for (int j = 0; j < 4; ++j) b[j] = sW[kk][tx * 4 + j];
            #pragma unroll
            for (int i = 0; i < 4; ++i)
                #pragma unroll
                for (int j = 0; j < 4; ++j) acc[i][j] += a[i] * b[j];
        }
        __syncthreads();
    }
    #pragma unroll
    for (int i = 0; i < 4; ++i) {
        int m = bm + ty * 4 + i;
        #pragma unroll
        for (int j = 0; j < 4; ++j) {
            int n = bn + tx * 4 + j;
            float v = acc[i][j];
            if (bias) v += bias[n];
            if (ls)   v = v * ls[n] + resid[(size_t)m * Nn + n];
            C[(size_t)m * Nn + n] = v;
        }
    }
}

// ---------------- fused talking-heads attention: one block (256 thr) per query row --------
__global__ __launch_bounds__(256) void attn_kernel(
    const float* __restrict__ q, const float* __restrict__ kv,
    const float* __restrict__ scale, const float* __restrict__ mp,
    const float* __restrict__ mq, float* __restrict__ o)
{
    __shared__ float qrow[INNER_];
    __shared__ float s[H_][N_];
    __shared__ float p[H_][N_];
    __shared__ float smp[H_ * H_], smq[H_ * H_], ssc[H_];
    __shared__ float red[4];
    int bi = blockIdx.x;            // b*N + i
    int b = bi >> 8, i = bi & 255;
    int tid = threadIdx.x;
    for (int e = tid; e < INNER_; e += 256) qrow[e] = q[(size_t)bi * INNER_ + e];
    if (tid < H_ * H_) { smp[tid] = mp[tid]; smq[tid] = mq[tid]; }
    if (tid < H_) ssc[tid] = scale[tid];
    __syncthreads();
    int j = tid;                    // 256 threads == N
    const float* krow = &kv[((size_t)b * N_ + j) * (2 * INNER_)];
    #pragma unroll
    for (int h = 0; h < H_; ++h) {
        float acc = 0.f;
        #pragma unroll 8
        for (int d = 0; d < DH_; ++d) acc += qrow[h * DH_ + d] * krow[h * DH_ + d];
        s[h][j] = acc * ssc[h];
    }
    __syncthreads();
    float sm[H_];
    #pragma unroll
    for (int g = 0; g < H_; ++g) {
        float acc = 0.f;
        #pragma unroll
        for (int h = 0; h < H_; ++h) acc += s[h][j] * smp[h * H_ + g];
        sm[g] = (j == i) ? -1e30f : acc;
    }
    #pragma unroll
    for (int g = 0; g < H_; ++g) p[g][j] = sm[g];
    // softmax over j for each mixed head g
    for (int g = 0; g < H_; ++g) {
        float v = p[g][j];
        float m = block_reduce(v, red, 1);
        float e = __expf(v - m);
        float l = block_reduce(e, red, 0);
        p[g][j] = e / l;
    }
    __syncthreads();
    #pragma unroll
    for (int g = 0; g < H_; ++g) {
        float acc = 0.f;
        #pragma unroll
        for (int h = 0; h < H_; ++h) acc += p[h][j] * smq[h * H_ + g];
        sm[g] = acc;
    }
    __syncthreads();
    #pragma unroll
    for (int g = 0; g < H_; ++g) s[g][j] = sm[g];
    __syncthreads();
    // o[b,i,g*64+d] = sum_j attn2[g][j] * v[b,j,g*64+d]
    for (int e = tid; e < INNER_; e += 256) {
        int g = e >> 6;
        float acc = 0.f;
        const float* vbase = &kv[((size_t)b * N_) * (2 * INNER_) + INNER_ + e];
        for (int jj = 0; jj < N_; ++jj)
            acc += s[g][jj] * vbase[(size_t)jj * (2 * INNER_)];
        o[(size_t)bi * INNER_ + e] = acc;
    }
}

// ---------------- fused MLP: one block (256 thr) per token ----------------
__global__ __launch_bounds__(256) void mlp_kernel(
    const float* __restrict__ y, const float* __restrict__ w1,
    const float* __restrict__ b1, const float* __restrict__ w2,
    const float* __restrict__ b2, const float* __restrict__ ls2,
    float* __restrict__ xf)
{
    __shared__ float yrow[DIM_];
    __shared__ float hh[MLP_];
    size_t row = blockIdx.x;
    int tid = threadIdx.x;
    for (int e = tid; e < DIM_; e += 256) yrow[e] = y[row * DIM_ + e];
    __syncthreads();
    for (int k = tid; k < MLP_; k += 256) {
        float acc = b1[k];
        for (int d = 0; d < DIM_; ++d) acc += yrow[d] * w1[(size_t)d * MLP_ + k];
        hh[k] = 0.5f * acc * (1.0f + erff(acc * 0.70710678118f));  // exact gelu
    }
    __syncthreads();
    for (int e = tid; e < DIM_; e += 256) {
        float acc = b2[e];
        for (int k = 0; k < MLP_; ++k) acc += hh[k] * w2[(size_t)k * DIM_ + e];
        xf[row * DIM_ + e] = acc * ls2[e] + xf[row * DIM_ + e];
    }
}

extern "C" void kernel_launch(void* const* d_in, const int* in_sizes, int n_in,
                              void* d_out, int out_size, void* d_ws, size_t ws_size,
                              hipStream_t stream) {
    const float* x      = (const float*)d_in[0];
    const float* ln1_g  = (const float*)d_in[1];
    const float* ln1_b  = (const float*)d_in[2];
    const float* wq     = (const float*)d_in[3];
    const float* wkv    = (const float*)d_in[4];
    const float* scale  = (const float*)d_in[5];
    const float* mixp   = (const float*)d_in[6];
    const float* mixq   = (const float*)d_in[7];
    const float* wo     = (const float*)d_in[8];
    const float* bo     = (const float*)d_in[9];
    const float* ls1    = (const float*)d_in[10];
    const float* ln2_g  = (const float*)d_in[11];
    const float* ln2_b  = (const float*)d_in[12];
    const float* w1     = (const float*)d_in[13];
    const float* b1     = (const float*)d_in[14];
    const float* w2     = (const float*)d_in[15];
    const float* b2     = (const float*)d_in[16];
    const float* ls2    = (const float*)d_in[17];

    float* xf = (float*)d_ws;                 // T*DIM
    float* y  = xf + (size_t)T_ * DIM_;       // T*DIM
    float* q  = y  + (size_t)T_ * DIM_;       // T*INNER
    float* kv = q  + (size_t)T_ * INNER_;     // T*2*INNER
    float* o  = kv + (size_t)T_ * 2 * INNER_; // T*INNER

    size_t nBytes = (size_t)T_ * DIM_ * sizeof(float);
    hipMemcpyAsync(xf, x, nBytes, hipMemcpyDeviceToDevice, stream);

    for (int l = 0; l < DEPTH_; ++l) {
        const float* g1  = ln1_g + (size_t)l * DIM_;
        const float* bb1 = ln1_b + (size_t)l * DIM_;
        const float* wq_ = wq    + (size_t)l * DIM_ * INNER_;
        const float* wkv_= wkv   + (size_t)l * DIM_ * 2 * INNER_;
        const float* sc_ = scale + (size_t)l * H_;
        const float* mp_ = mixp  + (size_t)l * H_ * H_;
        const float* mq_ = mixq  + (size_t)l * H_ * H_;
        const float* wo_ = wo    + (size_t)l * INNER_ * DIM_;
        const float* bo_ = bo    + (size_t)l * DIM_;
        const float* l1_ = ls1   + (size_t)l * DIM_;
        const float* g2  = ln2_g + (size_t)l * DIM_;
        const float* bb2 = ln2_b + (size_t)l * DIM_;
        const float* w1_ = w1    + (size_t)l * DIM_ * MLP_;
        const float* b1_ = b1    + (size_t)l * MLP_;
        const float* w2_ = w2    + (size_t)l * MLP_ * DIM_;
        const float* b2_ = b2    + (size_t)l * DIM_;
        const float* l2_ = ls2   + (size_t)l * DIM_;

        ln_kernel<<<T_, 128, 0, stream>>>(xf, g1, bb1, y);
        gemm_kernel<<<dim3(T_ / 64, INNER_ / 64), 256, 0, stream>>>(
            y, wq_, nullptr, nullptr, nullptr, q, T_, DIM_, INNER_);
        gemm_kernel<<<dim3(T_ / 64, 2 * INNER_ / 64), 256, 0, stream>>>(
            y, wkv_, nullptr, nullptr, nullptr, kv, T_, DIM_, 2 * INNER_);
        attn_kernel<<<T_, 256, 0, stream>>>(q, kv, sc_, mp_, mq_, o);
        gemm_kernel<<<dim3(T_ / 64, DIM_ / 64), 256, 0, stream>>>(
            o, wo_, bo_, l1_, xf, xf, T_, INNER_, DIM_);
        ln_kernel<<<T_, 128, 0, stream>>>(xf, g2, bb2, y);
        mlp_kernel<<<T_, 256, 0, stream>>>(y, w1_, b1_, w2_, b2_, l2_, xf);
    }

    hipMemcpyAsync(d_out, xf, nBytes, hipMemcpyDeviceToDevice, stream);
}

// Round 3
// 9496.368 us; speedup vs baseline: 2.6245x; 2.6245x over previous
//
#include <hip/hip_runtime.h>
#include <hip/hip_bf16.h>
#include <math.h>

#define B_ 32
#define N_ 256
#define DIM_ 384
#define H_ 6
#define DH_ 64
#define INNER_ 384
#define MLP_ 1536
#define DEPTH_ 12
#define T_ (B_ * N_)   // 8192 tokens

typedef __bf16 bf16x8 __attribute__((ext_vector_type(8)));
typedef __bf16 bf16x2 __attribute__((ext_vector_type(2)));
typedef float f32x4 __attribute__((ext_vector_type(4)));

// block-wide reduce (sum if op==0, max if op==1); all threads get result.
__device__ __forceinline__ float block_reduce(float v, float* scratch, int op) {
    int lane = threadIdx.x & 63;
    int wid  = threadIdx.x >> 6;
    int nw   = blockDim.x >> 6;
    #pragma unroll
    for (int o = 32; o > 0; o >>= 1) {
        float other = __shfl_down(v, o);
        v = op ? fmaxf(v, other) : (v + other);
    }
    __syncthreads();
    if (lane == 0) scratch[wid] = v;
    __syncthreads();
    float r = scratch[0];
    for (int w = 1; w < nw; ++w) r = op ? fmaxf(r, scratch[w]) : (r + scratch[w]);
    return r;
}

// ---------------- layernorm: one block (128 thr) per token ----------------
__global__ __launch_bounds__(128) void ln_kernel(
    const float* __restrict__ x, const float* __restrict__ g,
    const float* __restrict__ b, float* __restrict__ y)
{
    __shared__ float red[2];
    size_t row = blockIdx.x;
    int tid = threadIdx.x;
    const float* xr = x + row * DIM_;
    float v0 = xr[tid], v1 = xr[tid + 128], v2 = xr[tid + 256];
    float sum = block_reduce(v0 + v1 + v2, red, 0);
    float mu = sum * (1.0f / DIM_);
    float d0 = v0 - mu, d1 = v1 - mu, d2 = v2 - mu;
    float var = block_reduce(d0 * d0 + d1 * d1 + d2 * d2, red, 0) * (1.0f / DIM_);
    float rs = rsqrtf(var + 1e-5f);
    float* yr = y + row * DIM_;
    yr[tid]       = d0 * rs * g[tid]       + b[tid];
    yr[tid + 128] = d1 * rs * g[tid + 128] + b[tid + 128];
    yr[tid + 256] = d2 * rs * g[tid + 256] + b[tid + 256];
}

// ---------------- MFMA bf16 GEMM: C[M,Nn] = A[M,K] @ W[K,Nn] ----------------
// 128x128 tile, BK=32, 256 threads (4 waves, each 64x64 via 4x4 of 16x16x32 MFMA).
// fp32 global inputs, bf16 LDS staging, fp32 accumulate.
// mode 0: C = acc
// mode 1: C = gelu(acc + bias)
// mode 2: C = (acc + bias) * ls + resid
#define LDK 40   // padded k-stride (bf16 elems): 80B keeps 16B align, kills b128 conflicts

__global__ __launch_bounds__(256) void mfma_gemm(
    const float* __restrict__ A, const float* __restrict__ W,
    const float* __restrict__ bias, const float* __restrict__ ls,
    const float* __restrict__ resid, float* __restrict__ C,
    int M, int K, int Nn, int mode)
{
    __shared__ __bf16 sA[128 * LDK];
    __shared__ __bf16 sB[128 * LDK];
    int tid = threadIdx.x;
    int bm = blockIdx.x * 128, bn = blockIdx.y * 128;
    int lane = tid & 63, wid = tid >> 6;
    int wm = (wid & 1) * 64, wn = (wid >> 1) * 64;
    int fm = lane & 15, fq = lane >> 4;

    f32x4 acc[4][4] = {};

    // staging coords
    int sa_m = tid >> 1, sa_k = (tid & 1) << 4;          // A: 16 elems/thread
    int sb_k = (tid & 15) << 1, sb_n = (tid >> 4) << 3;  // B: 2 rows x 8 n /thread

    const float* aSrc = A + (size_t)(bm + sa_m) * K + sa_k;
    const float* wSrc = W + (size_t)sb_k * Nn + bn + sb_n;

    for (int k0 = 0; k0 < K; k0 += 32) {
        // ---- stage A tile (128x32) ----
        {
            const float4* s4 = (const float4*)aSrc;
            float4 f0 = s4[0], f1 = s4[1], f2 = s4[2], f3 = s4[3];
            bf16x8 v0 = { (__bf16)f0.x, (__bf16)f0.y, (__bf16)f0.z, (__bf16)f0.w,
                          (__bf16)f1.x, (__bf16)f1.y, (__bf16)f1.z, (__bf16)f1.w };
            bf16x8 v1 = { (__bf16)f2.x, (__bf16)f2.y, (__bf16)f2.z, (__bf16)f2.w,
                          (__bf16)f3.x, (__bf16)f3.y, (__bf16)f3.z, (__bf16)f3.w };
            *(bf16x8*)&sA[sa_m * LDK + sa_k]     = v0;
            *(bf16x8*)&sA[sa_m * LDK + sa_k + 8] = v1;
            aSrc += 32;
        }
        // ---- stage B tile (32x128), transposed to [n][k] ----
        {
            const float4* r0 = (const float4*)wSrc;
            const float4* r1 = (const float4*)(wSrc + Nn);
            float4 a0 = r0[0], a1 = r0[1];
            float4 c0 = r1[0], c1 = r1[1];
            float u0[8] = { a0.x, a0.y, a0.z, a0.w, a1.x, a1.y, a1.z, a1.w };
            float u1[8] = { c0.x, c0.y, c0.z, c0.w, c1.x, c1.y, c1.z, c1.w };
            #pragma unroll
            for (int w = 0; w < 8; ++w) {
                bf16x2 p = { (__bf16)u0[w], (__bf16)u1[w] };
                *(bf16x2*)&sB[(sb_n + w) * LDK + sb_k] = p;
            }
            wSrc += (size_t)32 * Nn;
        }
        __syncthreads();
        // ---- compute ----
        bf16x8 af[4], bf[4];
        #pragma unroll
        for (int i = 0; i < 4; ++i)
            af[i] = *(bf16x8*)&sA[(wm + i * 16 + fm) * LDK + (fq << 3)];
        #pragma unroll
        for (int j = 0; j < 4; ++j)
            bf[j] = *(bf16x8*)&sB[(wn + j * 16 + fm) * LDK + (fq << 3)];
        #pragma unroll
        for (int i = 0; i < 4; ++i)
            #pragma unroll
            for (int j = 0; j < 4; ++j)
                acc[i][j] = __builtin_amdgcn_mfma_f32_16x16x32_bf16(af[i], bf[j], acc[i][j], 0, 0, 0);
        __syncthreads();
    }

    // ---- epilogue: C/D layout col=lane&15, row=(lane>>4)*4+reg ----
    #pragma unroll
    for (int i = 0; i < 4; ++i) {
        #pragma unroll
        for (int j = 0; j < 4; ++j) {
            int col = bn + wn + j * 16 + fm;
            float bv = (mode != 0) ? bias[col] : 0.0f;
            float lv = (mode == 2) ? ls[col] : 0.0f;
            #pragma unroll
            for (int r = 0; r < 4; ++r) {
                int row = bm + wm + i * 16 + fq * 4 + r;
                float v = acc[i][j][r];
                if (mode == 1) {
                    v += bv;
                    v = 0.5f * v * (1.0f + erff(v * 0.70710678118f));
                } else if (mode == 2) {
                    v = (v + bv) * lv + resid[(size_t)row * Nn + col];
                }
                C[(size_t)row * Nn + col] = v;
            }
        }
    }
}

// ---------------- fused talking-heads attention: one block (256 thr) per query row --------
__global__ __launch_bounds__(256) void attn_kernel(
    const float* __restrict__ q, const float* __restrict__ kv,
    const float* __restrict__ scale, const float* __restrict__ mp,
    const float* __restrict__ mq, float* __restrict__ o)
{
    __shared__ float qrow[INNER_];
    __shared__ float s[H_][N_];
    __shared__ float p[H_][N_];
    __shared__ float smp[H_ * H_], smq[H_ * H_], ssc[H_];
    __shared__ float red[4];
    int bi = blockIdx.x;            // b*N + i
    int b = bi >> 8, i = bi & 255;
    int tid = threadIdx.x;
    for (int e = tid; e < INNER_; e += 256) qrow[e] = q[(size_t)bi * INNER_ + e];
    if (tid < H_ * H_) { smp[tid] = mp[tid]; smq[tid] = mq[tid]; }
    if (tid < H_) ssc[tid] = scale[tid];
    __syncthreads();
    int j = tid;                    // 256 threads == N
    const float* krow = &kv[((size_t)b * N_ + j) * (2 * INNER_)];
    #pragma unroll
    for (int h = 0; h < H_; ++h) {
        float acc = 0.f;
        #pragma unroll 8
        for (int d = 0; d < DH_; ++d) acc += qrow[h * DH_ + d] * krow[h * DH_ + d];
        s[h][j] = acc * ssc[h];
    }
    __syncthreads();
    float sm[H_];
    #pragma unroll
    for (int g = 0; g < H_; ++g) {
        float acc = 0.f;
        #pragma unroll
        for (int h = 0; h < H_; ++h) acc += s[h][j] * smp[h * H_ + g];
        sm[g] = (j == i) ? -1e30f : acc;
    }
    #pragma unroll
    for (int g = 0; g < H_; ++g) p[g][j] = sm[g];
    for (int g = 0; g < H_; ++g) {
        float v = p[g][j];
        float m = block_reduce(v, red, 1);
        float e = __expf(v - m);
        float l = block_reduce(e, red, 0);
        p[g][j] = e / l;
    }
    __syncthreads();
    #pragma unroll
    for (int g = 0; g < H_; ++g) {
        float acc = 0.f;
        #pragma unroll
        for (int h = 0; h < H_; ++h) acc += p[h][j] * smq[h * H_ + g];
        sm[g] = acc;
    }
    __syncthreads();
    #pragma unroll
    for (int g = 0; g < H_; ++g) s[g][j] = sm[g];
    __syncthreads();
    for (int e = tid; e < INNER_; e += 256) {
        int g = e >> 6;
        float acc = 0.f;
        const float* vbase = &kv[((size_t)b * N_) * (2 * INNER_) + INNER_ + e];
        for (int jj = 0; jj < N_; ++jj)
            acc += s[g][jj] * vbase[(size_t)jj * (2 * INNER_)];
        o[(size_t)bi * INNER_ + e] = acc;
    }
}

extern "C" void kernel_launch(void* const* d_in, const int* in_sizes, int n_in,
                              void* d_out, int out_size, void* d_ws, size_t ws_size,
                              hipStream_t stream) {
    const float* x      = (const float*)d_in[0];
    const float* ln1_g  = (const float*)d_in[1];
    const float* ln1_b  = (const float*)d_in[2];
    const float* wq     = (const float*)d_in[3];
    const float* wkv    = (const float*)d_in[4];
    const float* scale  = (const float*)d_in[5];
    const float* mixp   = (const float*)d_in[6];
    const float* mixq   = (const float*)d_in[7];
    const float* wo     = (const float*)d_in[8];
    const float* bo     = (const float*)d_in[9];
    const float* ls1    = (const float*)d_in[10];
    const float* ln2_g  = (const float*)d_in[11];
    const float* ln2_b  = (const float*)d_in[12];
    const float* w1     = (const float*)d_in[13];
    const float* b1     = (const float*)d_in[14];
    const float* w2     = (const float*)d_in[15];
    const float* b2     = (const float*)d_in[16];
    const float* ls2    = (const float*)d_in[17];

    float* xf = (float*)d_ws;                 // T*DIM
    float* y  = xf + (size_t)T_ * DIM_;       // T*DIM
    float* q  = y  + (size_t)T_ * DIM_;       // T*INNER
    float* kv = q  + (size_t)T_ * INNER_;     // T*2*INNER
    float* o  = kv + (size_t)T_ * 2 * INNER_; // T*INNER
    float* h  = q;                            // MLP hidden (T*MLP fp32) overlays q+kv+o (dead then)

    size_t nBytes = (size_t)T_ * DIM_ * sizeof(float);
    hipMemcpyAsync(xf, x, nBytes, hipMemcpyDeviceToDevice, stream);

    for (int l = 0; l < DEPTH_; ++l) {
        const float* g1  = ln1_g + (size_t)l * DIM_;
        const float* bb1 = ln1_b + (size_t)l * DIM_;
        const float* wq_ = wq    + (size_t)l * DIM_ * INNER_;
        const float* wkv_= wkv   + (size_t)l * DIM_ * 2 * INNER_;
        const float* sc_ = scale + (size_t)l * H_;
        const float* mp_ = mixp  + (size_t)l * H_ * H_;
        const float* mq_ = mixq  + (size_t)l * H_ * H_;
        const float* wo_ = wo    + (size_t)l * INNER_ * DIM_;
        const float* bo_ = bo    + (size_t)l * DIM_;
        const float* l1_ = ls1   + (size_t)l * DIM_;
        const float* g2  = ln2_g + (size_t)l * DIM_;
        const float* bb2 = ln2_b + (size_t)l * DIM_;
        const float* w1_ = w1    + (size_t)l * DIM_ * MLP_;
        const float* b1_ = b1    + (size_t)l * MLP_;
        const float* w2_ = w2    + (size_t)l * MLP_ * DIM_;
        const float* b2_ = b2    + (size_t)l * DIM_;
        const float* l2_ = ls2   + (size_t)l * DIM_;

        ln_kernel<<<T_, 128, 0, stream>>>(xf, g1, bb1, y);
        mfma_gemm<<<dim3(T_ / 128, INNER_ / 128), 256, 0, stream>>>(
            y, wq_, nullptr, nullptr, nullptr, q, T_, DIM_, INNER_, 0);
        mfma_gemm<<<dim3(T_ / 128, 2 * INNER_ / 128), 256, 0, stream>>>(
            y, wkv_, nullptr, nullptr, nullptr, kv, T_, DIM_, 2 * INNER_, 0);
        attn_kernel<<<T_, 256, 0, stream>>>(q, kv, sc_, mp_, mq_, o);
        mfma_gemm<<<dim3(T_ / 128, DIM_ / 128), 256, 0, stream>>>(
            o, wo_, bo_, l1_, xf, xf, T_, INNER_, DIM_, 2);
        ln_kernel<<<T_, 128, 0, stream>>>(xf, g2, bb2, y);
        mfma_gemm<<<dim3(T_ / 128, MLP_ / 128), 256, 0, stream>>>(
            y, w1_, b1_, nullptr, nullptr, h, T_, DIM_, MLP_, 1);
        mfma_gemm<<<dim3(T_ / 128, DIM_ / 128), 256, 0, stream>>>(
            h, w2_, b2_, l2_, xf, xf, T_, MLP_, DIM_, 2);
    }

    hipMemcpyAsync(d_out, xf, nBytes, hipMemcpyDeviceToDevice, stream);
}

// Round 4
// 4114.817 us; speedup vs baseline: 6.0568x; 2.3078x over previous
//
#include <hip/hip_runtime.h>
#include <hip/hip_bf16.h>
#include <math.h>

#define B_ 32
#define N_ 256
#define DIM_ 384
#define H_ 6
#define DH_ 64
#define INNER_ 384
#define MLP_ 1536
#define DEPTH_ 12
#define T_ (B_ * N_)   // 8192 tokens

typedef __bf16 bf16x8 __attribute__((ext_vector_type(8)));
typedef __bf16 bf16x4 __attribute__((ext_vector_type(4)));
typedef __bf16 bf16x2 __attribute__((ext_vector_type(2)));
typedef float f32x4 __attribute__((ext_vector_type(4)));

// block-wide reduce (sum if op==0, max if op==1); all threads get result.
__device__ __forceinline__ float block_reduce(float v, float* scratch, int op) {
    int lane = threadIdx.x & 63;
    int wid  = threadIdx.x >> 6;
    int nw   = blockDim.x >> 6;
    #pragma unroll
    for (int o = 32; o > 0; o >>= 1) {
        float other = __shfl_down(v, o);
        v = op ? fmaxf(v, other) : (v + other);
    }
    __syncthreads();
    if (lane == 0) scratch[wid] = v;
    __syncthreads();
    float r = scratch[0];
    for (int w = 1; w < nw; ++w) r = op ? fmaxf(r, scratch[w]) : (r + scratch[w]);
    return r;
}

// ---------------- layernorm: one block (128 thr) per token ----------------
__global__ __launch_bounds__(128) void ln_kernel(
    const float* __restrict__ x, const float* __restrict__ g,
    const float* __restrict__ b, float* __restrict__ y)
{
    __shared__ float red[2];
    size_t row = blockIdx.x;
    int tid = threadIdx.x;
    const float* xr = x + row * DIM_;
    float v0 = xr[tid], v1 = xr[tid + 128], v2 = xr[tid + 256];
    float sum = block_reduce(v0 + v1 + v2, red, 0);
    float mu = sum * (1.0f / DIM_);
    float d0 = v0 - mu, d1 = v1 - mu, d2 = v2 - mu;
    float var = block_reduce(d0 * d0 + d1 * d1 + d2 * d2, red, 0) * (1.0f / DIM_);
    float rs = rsqrtf(var + 1e-5f);
    float* yr = y + row * DIM_;
    yr[tid]       = d0 * rs * g[tid]       + b[tid];
    yr[tid + 128] = d1 * rs * g[tid + 128] + b[tid + 128];
    yr[tid + 256] = d2 * rs * g[tid + 256] + b[tid + 256];
}

// ---------------- MFMA bf16 GEMM: C[M,Nn] = A[M,K] @ W[K,Nn] ----------------
// 128x128 tile, BK=32, 256 threads (4 waves, each 64x64 via 4x4 of 16x16x32 MFMA).
// fp32 global inputs, bf16 LDS staging, fp32 accumulate.
// mode 0: C = acc
// mode 1: C = gelu(acc + bias)
// mode 2: C = (acc + bias) * ls + resid
// mode 3: KV split: col<384 -> C (K, stride 384); col>=384 -> C2 = vT[b][d][j] transposed
#define LDK 40   // padded k-stride (bf16 elems)

__global__ __launch_bounds__(256) void mfma_gemm(
    const float* __restrict__ A, const float* __restrict__ W,
    const float* __restrict__ bias, const float* __restrict__ ls,
    const float* __restrict__ resid, float* __restrict__ C,
    float* __restrict__ C2, int M, int K, int Nn, int mode)
{
    __shared__ __bf16 sA[128 * LDK];
    __shared__ __bf16 sB[128 * LDK];
    int tid = threadIdx.x;
    int bm = blockIdx.x * 128, bn = blockIdx.y * 128;
    int lane = tid & 63, wid = tid >> 6;
    int wm = (wid & 1) * 64, wn = (wid >> 1) * 64;
    int fm = lane & 15, fq = lane >> 4;

    f32x4 acc[4][4] = {};

    int sa_m = tid >> 1, sa_k = (tid & 1) << 4;          // A: 16 elems/thread
    int sb_k = (tid & 15) << 1, sb_n = (tid >> 4) << 3;  // B: 2 rows x 8 n /thread

    const float* aSrc = A + (size_t)(bm + sa_m) * K + sa_k;
    const float* wSrc = W + (size_t)sb_k * Nn + bn + sb_n;

    for (int k0 = 0; k0 < K; k0 += 32) {
        {
            const float4* s4 = (const float4*)aSrc;
            float4 f0 = s4[0], f1 = s4[1], f2 = s4[2], f3 = s4[3];
            bf16x8 v0 = { (__bf16)f0.x, (__bf16)f0.y, (__bf16)f0.z, (__bf16)f0.w,
                          (__bf16)f1.x, (__bf16)f1.y, (__bf16)f1.z, (__bf16)f1.w };
            bf16x8 v1 = { (__bf16)f2.x, (__bf16)f2.y, (__bf16)f2.z, (__bf16)f2.w,
                          (__bf16)f3.x, (__bf16)f3.y, (__bf16)f3.z, (__bf16)f3.w };
            *(bf16x8*)&sA[sa_m * LDK + sa_k]     = v0;
            *(bf16x8*)&sA[sa_m * LDK + sa_k + 8] = v1;
            aSrc += 32;
        }
        {
            const float4* r0 = (const float4*)wSrc;
            const float4* r1 = (const float4*)(wSrc + Nn);
            float4 a0 = r0[0], a1 = r0[1];
            float4 c0 = r1[0], c1 = r1[1];
            float u0[8] = { a0.x, a0.y, a0.z, a0.w, a1.x, a1.y, a1.z, a1.w };
            float u1[8] = { c0.x, c0.y, c0.z, c0.w, c1.x, c1.y, c1.z, c1.w };
            #pragma unroll
            for (int w = 0; w < 8; ++w) {
                bf16x2 p = { (__bf16)u0[w], (__bf16)u1[w] };
                *(bf16x2*)&sB[(sb_n + w) * LDK + sb_k] = p;
            }
            wSrc += (size_t)32 * Nn;
        }
        __syncthreads();
        bf16x8 af[4], bff[4];
        #pragma unroll
        for (int i = 0; i < 4; ++i)
            af[i] = *(bf16x8*)&sA[(wm + i * 16 + fm) * LDK + (fq << 3)];
        #pragma unroll
        for (int j = 0; j < 4; ++j)
            bff[j] = *(bf16x8*)&sB[(wn + j * 16 + fm) * LDK + (fq << 3)];
        #pragma unroll
        for (int i = 0; i < 4; ++i)
            #pragma unroll
            for (int j = 0; j < 4; ++j)
                acc[i][j] = __builtin_amdgcn_mfma_f32_16x16x32_bf16(af[i], bff[j], acc[i][j], 0, 0, 0);
        __syncthreads();
    }

    // epilogue: C/D layout col=lane&15, row=(lane>>4)*4+reg
    #pragma unroll
    for (int i = 0; i < 4; ++i) {
        #pragma unroll
        for (int j = 0; j < 4; ++j) {
            int col = bn + wn + j * 16 + fm;
            float bv = (mode == 1 || mode == 2) ? bias[col] : 0.0f;
            float lv = (mode == 2) ? ls[col] : 0.0f;
            #pragma unroll
            for (int r = 0; r < 4; ++r) {
                int row = bm + wm + i * 16 + fq * 4 + r;
                float v = acc[i][j][r];
                if (mode == 1) {
                    v += bv;
                    v = 0.5f * v * (1.0f + erff(v * 0.70710678118f));
                } else if (mode == 2) {
                    v = (v + bv) * lv + resid[(size_t)row * Nn + col];
                }
                if (mode == 3) {
                    if (col < 384) {
                        C[(size_t)row * 384 + col] = v;
                    } else {
                        int bb = row >> 8, jj = row & 255;
                        C2[((size_t)bb * 384 + (col - 384)) * 256 + jj] = v;
                    }
                } else {
                    C[(size_t)row * Nn + col] = v;
                }
            }
        }
    }
}

// ---------------- fused MFMA talking-heads attention ----------------
// Block = (itile 16 queries, batch). 384 threads = 6 waves, wave = head.
// kbuf: K [tok][384] fp32; vT: [b][384 d][256 j] fp32.
#define PAD_S 264   // sbuf row stride (bf16), mult of 8
#define PAD_K 392   // K-chunk row stride
#define PAD_V 72    // V-chunk row stride

__global__ __launch_bounds__(384) void attn_mfma(
    const float* __restrict__ q, const float* __restrict__ kbuf,
    const float* __restrict__ vT, const float* __restrict__ scale,
    const float* __restrict__ mp, const float* __restrict__ mq,
    float* __restrict__ o)
{
    __shared__ __bf16 qb[16][PAD_K];
    __shared__ union { __bf16 k[64][PAD_K]; __bf16 v[384][PAD_V]; } st;
    __shared__ __bf16 sbuf[96][PAD_S];
    __shared__ float smp[36], smq[36];

    int itile = blockIdx.x, b = blockIdx.y;
    int i0 = itile * 16;
    int tid = threadIdx.x;
    int lane = tid & 63, wid = tid >> 6;
    int fm = lane & 15, fq = lane >> 4;

    if (tid < 36) {
        int h = tid / 6;
        smp[tid] = mp[tid] * scale[h];   // fold per-head scale into pre-mix
        smq[tid] = mq[tid];
    }
    // stage Q tile (16 x 384) as bf16
    {
        int d4 = tid % 96, qq = tid / 96;
        #pragma unroll
        for (int r = 0; r < 4; ++r) {
            int qrow = qq + r * 4;
            float4 f = *(const float4*)&q[((size_t)(b * 256 + i0 + qrow)) * 384 + d4 * 4];
            bf16x4 t = { (__bf16)f.x, (__bf16)f.y, (__bf16)f.z, (__bf16)f.w };
            *(bf16x4*)&qb[qrow][d4 * 4] = t;
        }
    }
    __syncthreads();

    // ---- QK^T: wave h computes S_h[16][256] in 64-j chunks ----
    int h = wid;
    for (int jc = 0; jc < 4; ++jc) {
        int j0 = jc * 64;
        {
            int d4 = tid % 96, jj = tid / 96;
            #pragma unroll
            for (int r = 0; r < 16; ++r) {
                int j = jj + r * 4;
                float4 f = *(const float4*)&kbuf[((size_t)(b * 256 + j0 + j)) * 384 + d4 * 4];
                bf16x4 t = { (__bf16)f.x, (__bf16)f.y, (__bf16)f.z, (__bf16)f.w };
                *(bf16x4*)&st.k[j][d4 * 4] = t;
            }
        }
        __syncthreads();
        #pragma unroll
        for (int jt = 0; jt < 4; ++jt) {
            f32x4 a = {};
            #pragma unroll
            for (int ks = 0; ks < 2; ++ks) {
                bf16x8 af = *(const bf16x8*)&qb[fm][h * 64 + ks * 32 + fq * 8];
                bf16x8 bf = *(const bf16x8*)&st.k[jt * 16 + fm][h * 64 + ks * 32 + fq * 8];
                a = __builtin_amdgcn_mfma_f32_16x16x32_bf16(af, bf, a, 0, 0, 0);
            }
            #pragma unroll
            for (int r = 0; r < 4; ++r)
                sbuf[h * 16 + fq * 4 + r][j0 + jt * 16 + fm] = (__bf16)a[r];
        }
        __syncthreads();
    }

    // ---- pre-softmax head mix (+ diagonal mask); thread-local in-place ----
    for (int idx = tid; idx < 4096; idx += 384) {
        int qq = idx >> 8, j = idx & 255;
        float sv[6], ov[6];
        #pragma unroll
        for (int h2 = 0; h2 < 6; ++h2) sv[h2] = (float)sbuf[h2 * 16 + qq][j];
        #pragma unroll
        for (int g = 0; g < 6; ++g) {
            float r2 = 0.f;
            #pragma unroll
            for (int h2 = 0; h2 < 6; ++h2) r2 += sv[h2] * smp[h2 * 6 + g];
            ov[g] = (j == i0 + qq) ? -1e30f : r2;
        }
        #pragma unroll
        for (int g = 0; g < 6; ++g) sbuf[g * 16 + qq][j] = (__bf16)ov[g];
    }
    __syncthreads();

    // ---- softmax over j: wave w owns rows w*16..w*16+15 ----
    for (int rr = 0; rr < 16; ++rr) {
        int row = wid * 16 + rr;
        bf16x4 v4 = *(const bf16x4*)&sbuf[row][lane * 4];
        float v0 = (float)v4[0], v1 = (float)v4[1], v2 = (float)v4[2], v3 = (float)v4[3];
        float m = fmaxf(fmaxf(v0, v1), fmaxf(v2, v3));
        #pragma unroll
        for (int off = 32; off > 0; off >>= 1) m = fmaxf(m, __shfl_xor(m, off));
        float e0 = expf(v0 - m), e1 = expf(v1 - m), e2 = expf(v2 - m), e3 = expf(v3 - m);
        float s = e0 + e1 + e2 + e3;
        #pragma unroll
        for (int off = 32; off > 0; off >>= 1) s += __shfl_xor(s, off);
        float inv = 1.0f / s;
        bf16x4 w4 = { (__bf16)(e0 * inv), (__bf16)(e1 * inv), (__bf16)(e2 * inv), (__bf16)(e3 * inv) };
        *(bf16x4*)&sbuf[row][lane * 4] = w4;
    }
    __syncthreads();

    // ---- post-softmax head mix; thread-local in-place ----
    for (int idx = tid; idx < 4096; idx += 384) {
        int qq = idx >> 8, j = idx & 255;
        float sv[6], ov[6];
        #pragma unroll
        for (int h2 = 0; h2 < 6; ++h2) sv[h2] = (float)sbuf[h2 * 16 + qq][j];
        #pragma unroll
        for (int g = 0; g < 6; ++g) {
            float r2 = 0.f;
            #pragma unroll
            for (int h2 = 0; h2 < 6; ++h2) r2 += sv[h2] * smq[h2 * 6 + g];
            ov[g] = r2;
        }
        #pragma unroll
        for (int g = 0; g < 6; ++g) sbuf[g * 16 + qq][j] = (__bf16)ov[g];
    }
    __syncthreads();

    // ---- P @ V: wave g computes O_g[16][64] over j chunks ----
    int g = wid;
    f32x4 acco[4] = {};
    for (int jc = 0; jc < 4; ++jc) {
        int j0 = jc * 64;
        {
            int j4 = tid & 15, dd = tid >> 4;
            #pragma unroll
            for (int r = 0; r < 16; ++r) {
                int d = dd + r * 24;
                float4 f = *(const float4*)&vT[((size_t)b * 384 + d) * 256 + j0 + j4 * 4];
                bf16x4 t = { (__bf16)f.x, (__bf16)f.y, (__bf16)f.z, (__bf16)f.w };
                *(bf16x4*)&st.v[d][j4 * 4] = t;
            }
        }
        __syncthreads();
        #pragma unroll
        for (int ks = 0; ks < 2; ++ks) {
            bf16x8 af = *(const bf16x8*)&sbuf[g * 16 + fm][j0 + ks * 32 + fq * 8];
            #pragma unroll
            for (int nt = 0; nt < 4; ++nt) {
                bf16x8 bf = *(const bf16x8*)&st.v[g * 64 + nt * 16 + fm][ks * 32 + fq * 8];
                acco[nt] = __builtin_amdgcn_mfma_f32_16x16x32_bf16(af, bf, acco[nt], 0, 0, 0);
            }
        }
        __syncthreads();
    }
    #pragma unroll
    for (int nt = 0; nt < 4; ++nt)
        #pragma unroll
        for (int r = 0; r < 4; ++r)
            o[((size_t)(b * 256 + i0 + fq * 4 + r)) * 384 + g * 64 + nt * 16 + fm] = acco[nt][r];
}

extern "C" void kernel_launch(void* const* d_in, const int* in_sizes, int n_in,
                              void* d_out, int out_size, void* d_ws, size_t ws_size,
                              hipStream_t stream) {
    const float* x      = (const float*)d_in[0];
    const float* ln1_g  = (const float*)d_in[1];
    const float* ln1_b  = (const float*)d_in[2];
    const float* wq     = (const float*)d_in[3];
    const float* wkv    = (const float*)d_in[4];
    const float* scale  = (const float*)d_in[5];
    const float* mixp   = (const float*)d_in[6];
    const float* mixq   = (const float*)d_in[7];
    const float* wo     = (const float*)d_in[8];
    const float* bo     = (const float*)d_in[9];
    const float* ls1    = (const float*)d_in[10];
    const float* ln2_g  = (const float*)d_in[11];
    const float* ln2_b  = (const float*)d_in[12];
    const float* w1     = (const float*)d_in[13];
    const float* b1     = (const float*)d_in[14];
    const float* w2     = (const float*)d_in[15];
    const float* b2     = (const float*)d_in[16];
    const float* ls2    = (const float*)d_in[17];

    float* xf = (float*)d_ws;                 // T*DIM
    float* y  = xf + (size_t)T_ * DIM_;       // T*DIM
    float* q  = y  + (size_t)T_ * DIM_;       // T*INNER
    float* kb = q  + (size_t)T_ * INNER_;     // K [tok][384]
    float* vT = kb + (size_t)T_ * INNER_;     // V^T [b][384][256]
    float* o  = vT + (size_t)T_ * INNER_;     // T*INNER
    float* h  = q;                            // MLP hidden overlays q+kb+vT+o

    size_t nBytes = (size_t)T_ * DIM_ * sizeof(float);
    hipMemcpyAsync(xf, x, nBytes, hipMemcpyDeviceToDevice, stream);

    for (int l = 0; l < DEPTH_; ++l) {
        const float* g1  = ln1_g + (size_t)l * DIM_;
        const float* bb1 = ln1_b + (size_t)l * DIM_;
        const float* wq_ = wq    + (size_t)l * DIM_ * INNER_;
        const float* wkv_= wkv   + (size_t)l * DIM_ * 2 * INNER_;
        const float* sc_ = scale + (size_t)l * H_;
        const float* mp_ = mixp  + (size_t)l * H_ * H_;
        const float* mq_ = mixq  + (size_t)l * H_ * H_;
        const float* wo_ = wo    + (size_t)l * INNER_ * DIM_;
        const float* bo_ = bo    + (size_t)l * DIM_;
        const float* l1_ = ls1   + (size_t)l * DIM_;
        const float* g2  = ln2_g + (size_t)l * DIM_;
        const float* bb2 = ln2_b + (size_t)l * DIM_;
        const float* w1_ = w1    + (size_t)l * DIM_ * MLP_;
        const float* b1_ = b1    + (size_t)l * MLP_;
        const float* w2_ = w2    + (size_t)l * MLP_ * DIM_;
        const float* b2_ = b2    + (size_t)l * DIM_;
        const float* l2_ = ls2   + (size_t)l * DIM_;

        ln_kernel<<<T_, 128, 0, stream>>>(xf, g1, bb1, y);
        mfma_gemm<<<dim3(T_ / 128, INNER_ / 128), 256, 0, stream>>>(
            y, wq_, nullptr, nullptr, nullptr, q, nullptr, T_, DIM_, INNER_, 0);
        mfma_gemm<<<dim3(T_ / 128, 2 * INNER_ / 128), 256, 0, stream>>>(
            y, wkv_, nullptr, nullptr, nullptr, kb, vT, T_, DIM_, 2 * INNER_, 3);
        attn_mfma<<<dim3(16, 32), 384, 0, stream>>>(q, kb, vT, sc_, mp_, mq_, o);
        mfma_gemm<<<dim3(T_ / 128, DIM_ / 128), 256, 0, stream>>>(
            o, wo_, bo_, l1_, xf, xf, nullptr, T_, INNER_, DIM_, 2);
        ln_kernel<<<T_, 128, 0, stream>>>(xf, g2, bb2, y);
        mfma_gemm<<<dim3(T_ / 128, MLP_ / 128), 256, 0, stream>>>(
            y, w1_, b1_, nullptr, nullptr, h, nullptr, T_, DIM_, MLP_, 1);
        mfma_gemm<<<dim3(T_ / 128, DIM_ / 128), 256, 0, stream>>>(
            h, w2_, b2_, l2_, xf, xf, nullptr, T_, MLP_, DIM_, 2);
    }

    hipMemcpyAsync(d_out, xf, nBytes, hipMemcpyDeviceToDevice, stream);
}

// Round 6
// 2901.054 us; speedup vs baseline: 8.5909x; 1.4184x over previous
//
#include <hip/hip_runtime.h>
#include <hip/hip_bf16.h>
#include <math.h>

#define B_ 32
#define N_ 256
#define DIM_ 384
#define H_ 6
#define DH_ 64
#define INNER_ 384
#define MLP_ 1536
#define DEPTH_ 12
#define T_ (B_ * N_)   // 8192 tokens

typedef __bf16 bf16x8 __attribute__((ext_vector_type(8)));
typedef __bf16 bf16x4 __attribute__((ext_vector_type(4)));
typedef float f32x4 __attribute__((ext_vector_type(4)));

// wbuf layout (bf16, per layer, transposed [n][k])
#define WQKV_OFF 0                      // [1152][384]
#define WO_OFF   (1152 * 384)           // [384][384]
#define W1_OFF   (WO_OFF + 384 * 384)   // [1536][384]
#define W2_OFF   (W1_OFF + 1536 * 384)  // [384][1536]
#define WBUF_ELEMS (W2_OFF + 384 * 1536)

// block-wide reduce for LN (sum); scratch holds blockDim/64 floats
__device__ __forceinline__ float block_reduce_sum(float v, float* scratch) {
    int lane = threadIdx.x & 63;
    int wid  = threadIdx.x >> 6;
    int nw   = blockDim.x >> 6;
    #pragma unroll
    for (int o = 32; o > 0; o >>= 1) v += __shfl_down(v, o);
    __syncthreads();
    if (lane == 0) scratch[wid] = v;
    __syncthreads();
    float r = scratch[0];
    for (int w = 1; w < nw; ++w) r += scratch[w];
    return r;
}

// ---------------- weight pre-pack: fp32 [K][N] -> bf16 [n][k], one layer ----------------
__global__ __launch_bounds__(64) void convert_w(
    const float* __restrict__ wq, const float* __restrict__ wkv,
    const float* __restrict__ wo, const float* __restrict__ w1,
    const float* __restrict__ w2, __bf16* __restrict__ wbuf)
{
    __shared__ float til[64][65];
    int t = blockIdx.x, lane = threadIdx.x;
    const float* src; __bf16* dst;
    int Ns, sc, dK, dR, k0;
    if (t < 108) {                      // wqkv_t [1152][384]
        int nt = t / 6, kt = t % 6;
        int n0 = nt * 64; k0 = kt * 64;
        dst = wbuf + WQKV_OFF; dK = 384; dR = n0;
        if (n0 < 384) { src = wq;  Ns = 384; sc = n0; }
        else          { src = wkv; Ns = 768; sc = n0 - 384; }
    } else if (t < 144) {               // wo_t [384][384]
        int u = t - 108; int nt = u / 6, kt = u % 6;
        src = wo; Ns = 384; sc = nt * 64;
        dst = wbuf + WO_OFF; dK = 384; dR = nt * 64; k0 = kt * 64;
    } else if (t < 288) {               // w1_t [1536][384]
        int u = t - 144; int nt = u / 6, kt = u % 6;
        src = w1; Ns = 1536; sc = nt * 64;
        dst = wbuf + W1_OFF; dK = 384; dR = nt * 64; k0 = kt * 64;
    } else {                            // w2_t [384][1536]
        int u = t - 288; int nt = u / 24, kt = u % 24;
        src = w2; Ns = 384; sc = nt * 64;
        dst = wbuf + W2_OFF; dK = 1536; dR = nt * 64; k0 = kt * 64;
    }
    #pragma unroll 8
    for (int i = 0; i < 64; ++i)
        til[i][lane] = src[(size_t)(k0 + i) * Ns + sc + lane];
    __syncthreads();
    #pragma unroll 8
    for (int i = 0; i < 64; ++i)
        dst[(size_t)(dR + i) * dK + k0 + lane] = (__bf16)til[lane][i];
}

// ---------------- layernorm: one block (128 thr) per token; fp32 in, bf16 out ----------
__global__ __launch_bounds__(128) void ln_kernel(
    const float* __restrict__ x, const float* __restrict__ g,
    const float* __restrict__ b, __bf16* __restrict__ y)
{
    __shared__ float red[2];
    size_t row = blockIdx.x;
    int tid = threadIdx.x;
    const float* xr = x + row * DIM_;
    float v0 = xr[tid], v1 = xr[tid + 128], v2 = xr[tid + 256];
    float sum = block_reduce_sum(v0 + v1 + v2, red);
    float mu = sum * (1.0f / DIM_);
    float d0 = v0 - mu, d1 = v1 - mu, d2 = v2 - mu;
    float var = block_reduce_sum(d0 * d0 + d1 * d1 + d2 * d2, red) * (1.0f / DIM_);
    float rs = rsqrtf(var + 1e-5f);
    __bf16* yr = y + row * DIM_;
    yr[tid]       = (__bf16)(d0 * rs * g[tid]       + b[tid]);
    yr[tid + 128] = (__bf16)(d1 * rs * g[tid + 128] + b[tid + 128]);
    yr[tid + 256] = (__bf16)(d2 * rs * g[tid + 256] + b[tid + 256]);
}

// ---------------- 1-wave LDS-free MFMA GEMM: tile 64x64, direct global fragments -------
// A bf16 [M][K], Bt bf16 [Nn][K].  mode 0: QKV route; 1: gelu->out; 2: (+bias)*ls+xf
__global__ __launch_bounds__(64) void gemm1w(
    const __bf16* __restrict__ A, const __bf16* __restrict__ Bt,
    const float* __restrict__ bias, const float* __restrict__ ls,
    float* __restrict__ xf, __bf16* __restrict__ out,
    __bf16* __restrict__ oq, __bf16* __restrict__ ok, __bf16* __restrict__ ov,
    int K, int Nn, int mode)
{
    int bm = blockIdx.x * 64, bn = blockIdx.y * 64;
    int lane = threadIdx.x;
    int fm = lane & 15, fq = lane >> 4;
    f32x4 acc[4][4] = {};

    const __bf16* aBase = A + (size_t)(bm + fm) * K + fq * 8;
    const __bf16* bBase = Bt + (size_t)(bn + fm) * K + fq * 8;
    size_t aRowStride = (size_t)16 * K;

    for (int k0 = 0; k0 < K; k0 += 32) {
        bf16x8 af[4], bf[4];
        #pragma unroll
        for (int i = 0; i < 4; ++i) af[i] = *(const bf16x8*)(aBase + aRowStride * i + k0);
        #pragma unroll
        for (int j = 0; j < 4; ++j) bf[j] = *(const bf16x8*)(bBase + aRowStride * j + k0);
        #pragma unroll
        for (int i = 0; i < 4; ++i)
            #pragma unroll
            for (int j = 0; j < 4; ++j)
                acc[i][j] = __builtin_amdgcn_mfma_f32_16x16x32_bf16(af[i], bf[j], acc[i][j], 0, 0, 0);
    }

    // epilogue: C/D layout col=lane&15, row=(lane>>4)*4+reg
    #pragma unroll
    for (int j = 0; j < 4; ++j) {
        int col = bn + j * 16 + fm;
        float bv = (mode != 0) ? bias[col] : 0.0f;
        float lv = (mode == 2) ? ls[col] : 0.0f;
        #pragma unroll
        for (int i = 0; i < 4; ++i) {
            #pragma unroll
            for (int r = 0; r < 4; ++r) {
                int row = bm + i * 16 + fq * 4 + r;
                float v = acc[i][j][r];
                if (mode == 0) {
                    if (col < 384)      oq[(size_t)row * 384 + col] = (__bf16)v;
                    else if (col < 768) ok[(size_t)row * 384 + col - 384] = (__bf16)v;
                    else {
                        int bb = row >> 8, jj = row & 255;
                        ov[((size_t)bb * 384 + (col - 768)) * 256 + jj] = (__bf16)v;
                    }
                } else if (mode == 1) {
                    v += bv;
                    v = 0.5f * v * (1.0f + erff(v * 0.70710678118f));
                    out[(size_t)row * Nn + col] = (__bf16)v;
                } else {
                    size_t idx = (size_t)row * Nn + col;
                    xf[idx] = (v + bv) * lv + xf[idx];
                }
            }
        }
    }
}

// ---------------- fused MFMA talking-heads attention ----------------
// Block = (16-query tile, batch). 384 threads = 6 waves, wave = head.
// q, kb: bf16 [tok][384]; vT: bf16 [b][384][256]. LDS: score buffer only.
#define PAD_S 264

__global__ __launch_bounds__(384) void attn_mfma(
    const __bf16* __restrict__ q, const __bf16* __restrict__ kb,
    const __bf16* __restrict__ vT, const float* __restrict__ scale,
    const float* __restrict__ mp, const float* __restrict__ mq,
    __bf16* __restrict__ o)
{
    __shared__ __bf16 sbuf[96][PAD_S];
    __shared__ float smp[36], smq[36];

    int i0 = blockIdx.x * 16, b = blockIdx.y;
    int tid = threadIdx.x;
    int lane = tid & 63, wid = tid >> 6;
    int fm = lane & 15, fq = lane >> 4;

    if (tid < 36) {
        smp[tid] = mp[tid] * scale[tid / 6];   // fold per-head scale into pre-mix
        smq[tid] = mq[tid];
    }

    // ---- QK^T: wave h computes S_h[16][256] ----
    int h = wid;
    bf16x8 qf[2];
    #pragma unroll
    for (int ks = 0; ks < 2; ++ks)
        qf[ks] = *(const bf16x8*)&q[(size_t)(b * 256 + i0 + fm) * 384 + h * 64 + ks * 32 + fq * 8];
    #pragma unroll 4
    for (int jt = 0; jt < 16; ++jt) {
        f32x4 a = {};
        #pragma unroll
        for (int ks = 0; ks < 2; ++ks) {
            bf16x8 bf = *(const bf16x8*)&kb[(size_t)(b * 256 + jt * 16 + fm) * 384 + h * 64 + ks * 32 + fq * 8];
            a = __builtin_amdgcn_mfma_f32_16x16x32_bf16(qf[ks], bf, a, 0, 0, 0);
        }
        #pragma unroll
        for (int r = 0; r < 4; ++r)
            sbuf[h * 16 + fq * 4 + r][jt * 16 + fm] = (__bf16)a[r];
    }
    __syncthreads();

    // ---- pre-softmax head mix (+ diag mask); thread-local in-place ----
    for (int idx = tid; idx < 4096; idx += 384) {
        int qq = idx >> 8, j = idx & 255;
        float sv[6], ovv[6];
        #pragma unroll
        for (int h2 = 0; h2 < 6; ++h2) sv[h2] = (float)sbuf[h2 * 16 + qq][j];
        #pragma unroll
        for (int g = 0; g < 6; ++g) {
            float r2 = 0.f;
            #pragma unroll
            for (int h2 = 0; h2 < 6; ++h2) r2 += sv[h2] * smp[h2 * 6 + g];
            ovv[g] = (j == i0 + qq) ? -1e30f : r2;
        }
        #pragma unroll
        for (int g = 0; g < 6; ++g) sbuf[g * 16 + qq][j] = (__bf16)ovv[g];
    }
    __syncthreads();

    // ---- softmax over j: wave w owns rows w*16..w*16+15 ----
    for (int rr = 0; rr < 16; ++rr) {
        int row = wid * 16 + rr;
        bf16x4 v4 = *(const bf16x4*)&sbuf[row][lane * 4];
        float v0 = (float)v4[0], v1 = (float)v4[1], v2 = (float)v4[2], v3 = (float)v4[3];
        float m = fmaxf(fmaxf(v0, v1), fmaxf(v2, v3));
        #pragma unroll
        for (int off = 32; off > 0; off >>= 1) m = fmaxf(m, __shfl_xor(m, off));
        float e0 = expf(v0 - m), e1 = expf(v1 - m), e2 = expf(v2 - m), e3 = expf(v3 - m);
        float s = e0 + e1 + e2 + e3;
        #pragma unroll
        for (int off = 32; off > 0; off >>= 1) s += __shfl_xor(s, off);
        float inv = 1.0f / s;
        bf16x4 w4 = { (__bf16)(e0 * inv), (__bf16)(e1 * inv), (__bf16)(e2 * inv), (__bf16)(e3 * inv) };
        *(bf16x4*)&sbuf[row][lane * 4] = w4;
    }
    __syncthreads();

    // ---- post-softmax head mix ----
    for (int idx = tid; idx < 4096; idx += 384) {
        int qq = idx >> 8, j = idx & 255;
        float sv[6], ovv[6];
        #pragma unroll
        for (int h2 = 0; h2 < 6; ++h2) sv[h2] = (float)sbuf[h2 * 16 + qq][j];
        #pragma unroll
        for (int g = 0; g < 6; ++g) {
            float r2 = 0.f;
            #pragma unroll
            for (int h2 = 0; h2 < 6; ++h2) r2 += sv[h2] * smq[h2 * 6 + g];
            ovv[g] = r2;
        }
        #pragma unroll
        for (int g = 0; g < 6; ++g) sbuf[g * 16 + qq][j] = (__bf16)ovv[g];
    }
    __syncthreads();

    // ---- P @ V: wave g computes O_g[16][64]; V frags direct from global ----
    int g = wid;
    f32x4 acco[4] = {};
    #pragma unroll
    for (int jc = 0; jc < 4; ++jc) {
        #pragma unroll
        for (int ks = 0; ks < 2; ++ks) {
            bf16x8 af = *(const bf16x8*)&sbuf[g * 16 + fm][jc * 64 + ks * 32 + fq * 8];
            #pragma unroll
            for (int nt = 0; nt < 4; ++nt) {
                bf16x8 bf = *(const bf16x8*)&vT[(size_t)(b * 384 + g * 64 + nt * 16 + fm) * 256 + jc * 64 + ks * 32 + fq * 8];
                acco[nt] = __builtin_amdgcn_mfma_f32_16x16x32_bf16(af, bf, acco[nt], 0, 0, 0);
            }
        }
    }
    #pragma unroll
    for (int nt = 0; nt < 4; ++nt)
        #pragma unroll
        for (int r = 0; r < 4; ++r)
            o[(size_t)(b * 256 + i0 + fq * 4 + r) * 384 + g * 64 + nt * 16 + fm] = (__bf16)acco[nt][r];
}

extern "C" void kernel_launch(void* const* d_in, const int* in_sizes, int n_in,
                              void* d_out, int out_size, void* d_ws, size_t ws_size,
                              hipStream_t stream) {
    const float* x      = (const float*)d_in[0];
    const float* ln1_g  = (const float*)d_in[1];
    const float* ln1_b  = (const float*)d_in[2];
    const float* wq     = (const float*)d_in[3];
    const float* wkv    = (const float*)d_in[4];
    const float* scale  = (const float*)d_in[5];
    const float* mixp   = (const float*)d_in[6];
    const float* mixq   = (const float*)d_in[7];
    const float* wo     = (const float*)d_in[8];
    const float* bo     = (const float*)d_in[9];
    const float* ls1    = (const float*)d_in[10];
    const float* ln2_g  = (const float*)d_in[11];
    const float* ln2_b  = (const float*)d_in[12];
    const float* w1     = (const float*)d_in[13];
    const float* b1     = (const float*)d_in[14];
    const float* w2     = (const float*)d_in[15];
    const float* b2     = (const float*)d_in[16];
    const float* ls2    = (const float*)d_in[17];

    char* ws = (char*)d_ws;
    float*  xf = (float*)ws;                      ws += (size_t)T_ * DIM_ * 4;
    __bf16* y  = (__bf16*)ws;                     ws += (size_t)T_ * DIM_ * 2;
    __bf16* q  = (__bf16*)ws;                     ws += (size_t)T_ * DIM_ * 2;
    __bf16* kb = (__bf16*)ws;                     ws += (size_t)T_ * DIM_ * 2;
    __bf16* vT = (__bf16*)ws;                     ws += (size_t)T_ * DIM_ * 2;
    __bf16* o  = (__bf16*)ws;                     ws += (size_t)T_ * DIM_ * 2;
    __bf16* wbuf = (__bf16*)ws;                   ws += (size_t)WBUF_ELEMS * 2;
    __bf16* h  = q;   // MLP hidden [T][1536] overlays q+kb+vT+o (dead by then)

    size_t nBytes = (size_t)T_ * DIM_ * sizeof(float);
    hipMemcpyAsync(xf, x, nBytes, hipMemcpyDeviceToDevice, stream);

    for (int l = 0; l < DEPTH_; ++l) {
        convert_w<<<432, 64, 0, stream>>>(
            wq + (size_t)l * DIM_ * INNER_, wkv + (size_t)l * DIM_ * 2 * INNER_,
            wo + (size_t)l * INNER_ * DIM_, w1 + (size_t)l * DIM_ * MLP_,
            w2 + (size_t)l * MLP_ * DIM_, wbuf);

        ln_kernel<<<T_, 128, 0, stream>>>(xf, ln1_g + (size_t)l * DIM_, ln1_b + (size_t)l * DIM_, y);

        gemm1w<<<dim3(T_ / 64, 1152 / 64), 64, 0, stream>>>(
            y, wbuf + WQKV_OFF, nullptr, nullptr, nullptr, nullptr,
            q, kb, vT, DIM_, 1152, 0);

        attn_mfma<<<dim3(16, 32), 384, 0, stream>>>(
            q, kb, vT, scale + (size_t)l * H_,
            mixp + (size_t)l * H_ * H_, mixq + (size_t)l * H_ * H_, o);

        gemm1w<<<dim3(T_ / 64, DIM_ / 64), 64, 0, stream>>>(
            o, wbuf + WO_OFF, bo + (size_t)l * DIM_, ls1 + (size_t)l * DIM_,
            xf, nullptr, nullptr, nullptr, nullptr, INNER_, DIM_, 2);

        ln_kernel<<<T_, 128, 0, stream>>>(xf, ln2_g + (size_t)l * DIM_, ln2_b + (size_t)l * DIM_, y);

        gemm1w<<<dim3(T_ / 64, MLP_ / 64), 64, 0, stream>>>(
            y, wbuf + W1_OFF, b1 + (size_t)l * MLP_, nullptr,
            nullptr, h, nullptr, nullptr, nullptr, DIM_, MLP_, 1);

        gemm1w<<<dim3(T_ / 64, DIM_ / 64), 64, 0, stream>>>(
            h, wbuf + W2_OFF, b2 + (size_t)l * DIM_, ls2 + (size_t)l * DIM_,
            xf, nullptr, nullptr, nullptr, nullptr, MLP_, DIM_, 2);
    }

    hipMemcpyAsync(d_out, xf, nBytes, hipMemcpyDeviceToDevice, stream);
}